// Round 1
// baseline (284.166 us; speedup 1.0000x reference)
//
#include <hip/hip_runtime.h>
#include <hip/hip_bf16.h>

typedef __bf16 bf16_t;
typedef bf16_t bf16x8 __attribute__((ext_vector_type(8)));
typedef float floatx4 __attribute__((ext_vector_type(4)));

#define N_NODES 100000
#define N_EDGES 1000000
#define NHID 128
#define PQ_COLS 256

// ---------------- kernel 1: feature f32 -> bf16 (12.8M elems, 8/thread) ----
__global__ __launch_bounds__(256) void k_convert(const float* __restrict__ f,
                                                 bf16_t* __restrict__ o) {
    int i = blockIdx.x * 256 + threadIdx.x;       // 1,600,000 total threads
    const float4* f4 = (const float4*)f;
    float4 u = f4[2 * i];
    float4 v = f4[2 * i + 1];
    bf16x8 r;
    r[0] = (bf16_t)u.x; r[1] = (bf16_t)u.y; r[2] = (bf16_t)u.z; r[3] = (bf16_t)u.w;
    r[4] = (bf16_t)v.x; r[5] = (bf16_t)v.y; r[6] = (bf16_t)v.z; r[7] = (bf16_t)v.w;
    ((bf16x8*)o)[i] = r;
}

// ---------------- kernel 2: build WT[n][k] = Wcat[k][n], bf16 [256,128] ----
// Wcat[k, n] = (n < 128) ? W1[k, n] : W1[k + 128, n - 128],  W1 is [256,128] row-major
__global__ __launch_bounds__(256) void k_build_wt(const float* __restrict__ W1,
                                                  bf16_t* __restrict__ WT) {
    int i = blockIdx.x * 256 + threadIdx.x;       // 32768 total
    int n = i >> 7;
    int k = i & 127;
    float v = (n < 128) ? W1[k * 128 + n] : W1[(k + 128) * 128 + (n - 128)];
    WT[i] = (bf16_t)v;
}

// ---------------- kernel 3: PQ = feature @ Wcat  ([100000,128]@[128,256]) --
// One wave computes a 16(M) x 64(N) strip via 4 accumulators of 16x16, K=128.
__global__ __launch_bounds__(256) void k_gemm_pq(const bf16_t* __restrict__ A,  // [M,128]
                                                 const bf16_t* __restrict__ WT, // [256,128]
                                                 bf16_t* __restrict__ PQ) {     // [M,256]
    int wave = threadIdx.x >> 6;              // 0..3
    int lane = threadIdx.x & 63;
    int task = blockIdx.x * 4 + wave;         // 0..24999
    int m_tile = task >> 2;                   // 0..6249
    int n_tile = task & 3;                    // 0..3
    int m0 = m_tile * 16;
    int n0 = n_tile * 64;
    int l15 = lane & 15;
    int quad = lane >> 4;

    floatx4 acc0 = {}, acc1 = {}, acc2 = {}, acc3 = {};
    const bf16_t* arow = A + (size_t)(m0 + l15) * NHID + quad * 8;

#pragma unroll
    for (int s = 0; s < 4; ++s) {
        int k0 = s * 32;
        bf16x8 a = *(const bf16x8*)(arow + k0);
        bf16x8 b0 = *(const bf16x8*)(WT + (size_t)(n0 + 0 * 16 + l15) * NHID + k0 + quad * 8);
        bf16x8 b1 = *(const bf16x8*)(WT + (size_t)(n0 + 1 * 16 + l15) * NHID + k0 + quad * 8);
        bf16x8 b2 = *(const bf16x8*)(WT + (size_t)(n0 + 2 * 16 + l15) * NHID + k0 + quad * 8);
        bf16x8 b3 = *(const bf16x8*)(WT + (size_t)(n0 + 3 * 16 + l15) * NHID + k0 + quad * 8);
        acc0 = __builtin_amdgcn_mfma_f32_16x16x32_bf16(a, b0, acc0, 0, 0, 0);
        acc1 = __builtin_amdgcn_mfma_f32_16x16x32_bf16(a, b1, acc1, 0, 0, 0);
        acc2 = __builtin_amdgcn_mfma_f32_16x16x32_bf16(a, b2, acc2, 0, 0, 0);
        acc3 = __builtin_amdgcn_mfma_f32_16x16x32_bf16(a, b3, acc3, 0, 0, 0);
    }
    // C/D layout: col = lane&15, row = (lane>>4)*4 + r
#pragma unroll
    for (int r = 0; r < 4; ++r) {
        size_t rowoff = (size_t)(m0 + quad * 4 + r) * PQ_COLS + n0 + l15;
        PQ[rowoff + 0]  = (bf16_t)acc0[r];
        PQ[rowoff + 16] = (bf16_t)acc1[r];
        PQ[rowoff + 32] = (bf16_t)acc2[r];
        PQ[rowoff + 48] = (bf16_t)acc3[r];
    }
}

// ---------------- kernel 4: per-edge loss, 16 lanes per edge ----------------
__global__ __launch_bounds__(256) void k_edge_loss(const bf16_t* __restrict__ PQ,
                                                   const float* __restrict__ b1,
                                                   const float* __restrict__ alpha,
                                                   const float* __restrict__ W2,
                                                   const float* __restrict__ b2,
                                                   const int* __restrict__ row,
                                                   const int* __restrict__ col,
                                                   const int* __restrict__ label,
                                                   float* __restrict__ out) {
    int lg = threadIdx.x & 15;                 // lane in 16-lane group
    int group = (blockIdx.x * blockDim.x + threadIdx.x) >> 4;
    int ngroups = (gridDim.x * blockDim.x) >> 4;
    int ch = lg * 8;

    float b1r[8], alr[8], w20[8], w21[8];
#pragma unroll
    for (int j = 0; j < 8; ++j) {
        b1r[j] = b1[ch + j];
        alr[j] = alpha[ch + j];
        w20[j] = W2[(ch + j) * 2 + 0];
        w21[j] = W2[(ch + j) * 2 + 1];
    }
    float bb0 = b2[0], bb1 = b2[1];

    float acc = 0.f;
    for (int e = group; e < N_EDGES; e += ngroups) {
        int r = row[e];
        int c = col[e];
        int y = (label[r] == label[c]) ? 1 : 0;
        bf16x8 p = *(const bf16x8*)(PQ + (size_t)r * PQ_COLS + ch);
        bf16x8 q = *(const bf16x8*)(PQ + (size_t)c * PQ_COLS + 128 + ch);
        float l0 = 0.f, l1 = 0.f;
#pragma unroll
        for (int j = 0; j < 8; ++j) {
            float h = (float)p[j] + (float)q[j] + b1r[j];
            h = (h >= 0.f) ? h : alr[j] * h;
            l0 = fmaf(h, w20[j], l0);
            l1 = fmaf(h, w21[j], l1);
        }
#pragma unroll
        for (int m = 8; m >= 1; m >>= 1) {
            l0 += __shfl_xor(l0, m, 16);
            l1 += __shfl_xor(l1, m, 16);
        }
        if (lg == 0) {
            l0 += bb0;
            l1 += bb1;
            float mx = fmaxf(l0, l1);
            float lse = mx + logf(expf(l0 - mx) + expf(l1 - mx));
            acc -= (y ? l1 : l0) - lse;
        }
    }
    // block reduction: wave butterfly then LDS across 4 waves
#pragma unroll
    for (int m = 32; m >= 1; m >>= 1) acc += __shfl_xor(acc, m, 64);
    __shared__ float sdata[4];
    int lane = threadIdx.x & 63;
    int wv = threadIdx.x >> 6;
    if (lane == 0) sdata[wv] = acc;
    __syncthreads();
    if (threadIdx.x == 0) {
        float s = (sdata[0] + sdata[1]) + (sdata[2] + sdata[3]);
        atomicAdd(out, s * (1.f / (float)N_EDGES));
    }
}

extern "C" void kernel_launch(void* const* d_in, const int* in_sizes, int n_in,
                              void* d_out, int out_size, void* d_ws, size_t ws_size,
                              hipStream_t stream) {
    const float* feature = (const float*)d_in[0];   // [100000,128]
    const float* W1      = (const float*)d_in[1];   // [256,128]
    const float* b1      = (const float*)d_in[2];   // [128]
    const float* alpha   = (const float*)d_in[3];   // [128]
    const float* W2      = (const float*)d_in[4];   // [128,2]
    const float* b2      = (const float*)d_in[5];   // [2]
    const int*   row     = (const int*)d_in[6];     // [1M]
    const int*   col     = (const int*)d_in[7];     // [1M]
    const int*   label   = (const int*)d_in[8];     // [100000]
    float* out = (float*)d_out;

    // workspace layout (all 256-B aligned)
    char* ws = (char*)d_ws;
    bf16_t* PQ   = (bf16_t*)(ws);                       // 100000*256*2 = 51,200,000 B
    bf16_t* Fb   = (bf16_t*)(ws + 51200000);            // 100000*128*2 = 25,600,000 B
    bf16_t* WT   = (bf16_t*)(ws + 76800000);            // 256*128*2    =     65,536 B

    hipMemsetAsync(d_out, 0, sizeof(float), stream);

    k_convert<<<6250, 256, 0, stream>>>(feature, Fb);       // 12.8M/8 per thread
    k_build_wt<<<128, 256, 0, stream>>>(W1, WT);            // 32768 elems
    k_gemm_pq<<<6250, 256, 0, stream>>>(Fb, WT, PQ);        // 25000 wave-tasks
    k_edge_loss<<<2048, 256, 0, stream>>>(PQ, b1, alpha, W2, b2, row, col, label, out);
}

// Round 2
// 239.054 us; speedup vs baseline: 1.1887x; 1.1887x over previous
//
#include <hip/hip_runtime.h>
#include <hip/hip_bf16.h>

typedef __bf16 bf16_t;
typedef bf16_t bf16x8 __attribute__((ext_vector_type(8)));
typedef float floatx4 __attribute__((ext_vector_type(4)));

#define N_NODES 100000
#define N_EDGES 1000000
#define NHID 128
#define PQ_COLS 256

// ---------------- kernel 1: build WT[n][k] = Wcat[k][n], bf16 [256,128] ----
// Wcat[k, n] = (n < 128) ? W1[k, n] : W1[k + 128, n - 128],  W1 is [256,128] row-major
__global__ __launch_bounds__(256) void k_build_wt(const float* __restrict__ W1,
                                                  bf16_t* __restrict__ WT) {
    int i = blockIdx.x * 256 + threadIdx.x;       // 32768 total
    int n = i >> 7;
    int k = i & 127;
    float v = (n < 128) ? W1[k * 128 + n] : W1[(k + 128) * 128 + (n - 128)];
    WT[i] = (bf16_t)v;
}

// ---------------- kernel 2: PQ = bf16(feature) @ Wcat, fused convert -------
// Block: 64 rows (M) x 256 cols (N), K=128. 4 waves, wave w covers n in
// [w*64, w*64+64). LDS holds the A-tile in MFMA-fragment order:
//   chunk(mt, s, quad, l15) = ((mt*4 + s)*4 + quad)*16 + l15   (16B chunks)
// so an A-fragment read is 64 consecutive 16B chunks -> conflict-free b128.
__global__ __launch_bounds__(256) void k_gemm_pq(const float* __restrict__ F,   // [100000,128] f32
                                                 const bf16_t* __restrict__ WT, // [256,128] bf16
                                                 bf16_t* __restrict__ PQ) {     // [100000,256] bf16
    __shared__ bf16x8 As8[1024];   // 16 KB: 4 mt * 4 s * 64 lanes
    const int t = threadIdx.x;
    const int m0 = blockIdx.x * 64;

    // ---- stage: 2048 float4 chunks, coalesced; convert f32->bf16 into LDS
#pragma unroll
    for (int j = 0; j < 8; ++j) {
        int chunk = j * 256 + t;           // 0..2047
        int r = chunk >> 5;                // row in tile 0..63
        int c4 = chunk & 31;               // float4 index within row
        int gr = m0 + r;
        float4 u;
        if (gr < N_NODES) u = ((const float4*)F)[(size_t)gr * 32 + c4];
        else { u.x = u.y = u.z = u.w = 0.f; }
        int s    = c4 >> 3;                // k-step 0..3
        int quad = (c4 >> 1) & 3;
        int half = c4 & 1;
        bf16_t* dst = (bf16_t*)&As8[(((r >> 4) * 4 + s) * 4 + quad) * 16 + (r & 15)] + half * 4;
        dst[0] = (bf16_t)u.x; dst[1] = (bf16_t)u.y; dst[2] = (bf16_t)u.z; dst[3] = (bf16_t)u.w;
    }
    __syncthreads();

    const int wave = t >> 6, lane = t & 63;
    const int l15 = lane & 15, quad = lane >> 4;
    const int n0 = wave * 64;

    floatx4 acc[4][4] = {};  // [mt][nt]
#pragma unroll
    for (int s = 0; s < 4; ++s) {
        bf16x8 a[4], b[4];
#pragma unroll
        for (int mt = 0; mt < 4; ++mt)
            a[mt] = As8[(mt * 4 + s) * 64 + lane];
#pragma unroll
        for (int nt = 0; nt < 4; ++nt)
            b[nt] = *(const bf16x8*)(WT + (size_t)(n0 + nt * 16 + l15) * NHID + s * 32 + quad * 8);
#pragma unroll
        for (int mt = 0; mt < 4; ++mt)
#pragma unroll
            for (int nt = 0; nt < 4; ++nt)
                acc[mt][nt] = __builtin_amdgcn_mfma_f32_16x16x32_bf16(a[mt], b[nt], acc[mt][nt], 0, 0, 0);
    }

    // ---- epilogue: row = m0 + mt*16 + quad*4 + r, col = n0 + nt*16 + l15
#pragma unroll
    for (int mt = 0; mt < 4; ++mt) {
#pragma unroll
        for (int r = 0; r < 4; ++r) {
            int grow = m0 + mt * 16 + quad * 4 + r;
            if (grow < N_NODES) {
                size_t base = (size_t)grow * PQ_COLS + n0 + l15;
#pragma unroll
                for (int nt = 0; nt < 4; ++nt)
                    PQ[base + nt * 16] = (bf16_t)acc[mt][nt][r];
            }
        }
    }
}

// ---------------- kernel 3: per-edge loss, 16 lanes/edge, 2-edge ILP -------
__global__ __launch_bounds__(256) void k_edge_loss(const bf16_t* __restrict__ PQ,
                                                   const float* __restrict__ b1,
                                                   const float* __restrict__ alpha,
                                                   const float* __restrict__ W2,
                                                   const float* __restrict__ b2,
                                                   const int* __restrict__ row,
                                                   const int* __restrict__ col,
                                                   const int* __restrict__ label,
                                                   float* __restrict__ out) {
    const int lg = threadIdx.x & 15;                 // lane in 16-lane group
    const int group = (blockIdx.x * blockDim.x + threadIdx.x) >> 4;
    const int ng = (gridDim.x * blockDim.x) >> 4;
    const int ch = lg * 8;

    float b1r[8], alr[8], w20[8], w21[8];
#pragma unroll
    for (int j = 0; j < 8; ++j) {
        b1r[j] = b1[ch + j];
        alr[j] = alpha[ch + j];
        w20[j] = W2[(ch + j) * 2 + 0];
        w21[j] = W2[(ch + j) * 2 + 1];
    }
    const float bb0 = b2[0], bb1 = b2[1];

    float acc = 0.f;
    for (int e = group; e < N_EDGES; e += 2 * ng) {
        const int e2 = e + ng;
        const bool has2 = (e2 < N_EDGES);
        int r1 = row[e], c1 = col[e];
        int r2 = has2 ? row[e2] : r1;
        int c2 = has2 ? col[e2] : c1;
        // issue all four gathers up front
        bf16x8 p1 = *(const bf16x8*)(PQ + (size_t)r1 * PQ_COLS + ch);
        bf16x8 q1 = *(const bf16x8*)(PQ + (size_t)c1 * PQ_COLS + 128 + ch);
        bf16x8 p2 = *(const bf16x8*)(PQ + (size_t)r2 * PQ_COLS + ch);
        bf16x8 q2 = *(const bf16x8*)(PQ + (size_t)c2 * PQ_COLS + 128 + ch);
        int y1 = (label[r1] == label[c1]) ? 1 : 0;
        int y2 = (label[r2] == label[c2]) ? 1 : 0;

        float a0 = 0.f, a1 = 0.f, d0 = 0.f, d1 = 0.f;
#pragma unroll
        for (int j = 0; j < 8; ++j) {
            float h1 = (float)p1[j] + (float)q1[j] + b1r[j];
            h1 = (h1 >= 0.f) ? h1 : alr[j] * h1;
            a0 = fmaf(h1, w20[j], a0);
            a1 = fmaf(h1, w21[j], a1);
            float h2 = (float)p2[j] + (float)q2[j] + b1r[j];
            h2 = (h2 >= 0.f) ? h2 : alr[j] * h2;
            d0 = fmaf(h2, w20[j], d0);
            d1 = fmaf(h2, w21[j], d1);
        }
#pragma unroll
        for (int m = 8; m >= 1; m >>= 1) {
            a0 += __shfl_xor(a0, m, 16);
            a1 += __shfl_xor(a1, m, 16);
            d0 += __shfl_xor(d0, m, 16);
            d1 += __shfl_xor(d1, m, 16);
        }
        if (lg == 0) {
            // loss = softplus(l_other - l_y), stable form
            float l0 = a0 + bb0, l1 = a1 + bb1;
            float d = y1 ? (l0 - l1) : (l1 - l0);
            acc += fmaxf(d, 0.f) + log1pf(expf(-fabsf(d)));
            if (has2) {
                float m0v = d0 + bb0, m1v = d1 + bb1;
                float dd = y2 ? (m0v - m1v) : (m1v - m0v);
                acc += fmaxf(dd, 0.f) + log1pf(expf(-fabsf(dd)));
            }
        }
    }
    // block reduction: wave butterfly then LDS across 4 waves
#pragma unroll
    for (int m = 32; m >= 1; m >>= 1) acc += __shfl_xor(acc, m, 64);
    __shared__ float sdata[4];
    int lane = threadIdx.x & 63;
    int wv = threadIdx.x >> 6;
    if (lane == 0) sdata[wv] = acc;
    __syncthreads();
    if (threadIdx.x == 0) {
        float s = (sdata[0] + sdata[1]) + (sdata[2] + sdata[3]);
        atomicAdd(out, s * (1.f / (float)N_EDGES));
    }
}

extern "C" void kernel_launch(void* const* d_in, const int* in_sizes, int n_in,
                              void* d_out, int out_size, void* d_ws, size_t ws_size,
                              hipStream_t stream) {
    const float* feature = (const float*)d_in[0];   // [100000,128]
    const float* W1      = (const float*)d_in[1];   // [256,128]
    const float* b1      = (const float*)d_in[2];   // [128]
    const float* alpha   = (const float*)d_in[3];   // [128]
    const float* W2      = (const float*)d_in[4];   // [128,2]
    const float* b2      = (const float*)d_in[5];   // [2]
    const int*   row     = (const int*)d_in[6];     // [1M]
    const int*   col     = (const int*)d_in[7];     // [1M]
    const int*   label   = (const int*)d_in[8];     // [100000]
    float* out = (float*)d_out;

    char* ws = (char*)d_ws;
    bf16_t* PQ = (bf16_t*)(ws);                 // 100000*256*2 = 51,200,000 B
    bf16_t* WT = (bf16_t*)(ws + 51200000);      // 256*128*2    =     65,536 B

    hipMemsetAsync(d_out, 0, sizeof(float), stream);

    k_build_wt<<<128, 256, 0, stream>>>(W1, WT);                 // 32768 elems
    k_gemm_pq<<<1563, 256, 0, stream>>>(feature, WT, PQ);        // 64 rows/block
    k_edge_loss<<<2048, 256, 0, stream>>>(PQ, b1, alpha, W2, b2, row, col, label, out);
}

// Round 3
// 212.433 us; speedup vs baseline: 1.3377x; 1.1253x over previous
//
#include <hip/hip_runtime.h>
#include <hip/hip_bf16.h>

typedef __bf16 bf16_t;
typedef bf16_t bf16x8 __attribute__((ext_vector_type(8)));
typedef float floatx4 __attribute__((ext_vector_type(4)));

#define N_NODES 100000
#define N_EDGES 1000000
#define NHID 128
#define PQ_COLS 256

// ---------------- kernel 1: prep — WT[n][k] = Wcat[k][n] bf16, wd vectors --
// Wcat[k, n] = (n < 128) ? W1[k, n] : W1[k + 128, n - 128],  W1 is [256,128] row-major
__global__ __launch_bounds__(256) void k_prep(const float* __restrict__ W1,
                                              const float* __restrict__ alpha,
                                              const float* __restrict__ W2,
                                              const float* __restrict__ b2,
                                              bf16_t* __restrict__ WT,
                                              float* __restrict__ wdp,
                                              float* __restrict__ wdn,
                                              float* __restrict__ dbias) {
    int i = blockIdx.x * 256 + threadIdx.x;       // 32768 total
    int n = i >> 7;
    int k = i & 127;
    float v = (n < 128) ? W1[k * 128 + n] : W1[(k + 128) * 128 + (n - 128)];
    WT[i] = (bf16_t)v;
    if (blockIdx.x == 0) {
        if (threadIdx.x < 128) {
            float wd = W2[threadIdx.x * 2 + 1] - W2[threadIdx.x * 2 + 0];
            wdp[threadIdx.x] = wd;
            wdn[threadIdx.x] = wd * alpha[threadIdx.x];
        } else if (threadIdx.x == 128) {
            *dbias = b2[1] - b2[0];
        }
    }
}

// ---------------- kernel 2: PQ = bf16(feature) @ Wcat + bias, fused convert
// Block: 64 rows x 256 cols, K=128. Bias = b1 on cols<128, 0 on cols>=128.
// Epilogue: LDS transpose (two 32x256 halves, col-swizzled) -> coalesced
// 16B/lane stores.
__global__ __launch_bounds__(256) void k_gemm_pq(const float* __restrict__ F,   // [100000,128] f32
                                                 const bf16_t* __restrict__ WT, // [256,128] bf16
                                                 const float* __restrict__ b1,  // [128] f32
                                                 bf16_t* __restrict__ PQ) {     // [100000,256] bf16
    __shared__ bf16x8 As8[1024];   // 16 KB, reused for epilogue tile
    const int t = threadIdx.x;
    const int m0 = blockIdx.x * 64;

    // ---- stage: 2048 float4 chunks, coalesced; convert f32->bf16 into LDS
    // LDS fragment order: chunk((r>>4), s, quad, r&15); a-frag read is
    // 64 consecutive 16B chunks -> conflict-free ds_read_b128.
#pragma unroll
    for (int j = 0; j < 8; ++j) {
        int chunk = j * 256 + t;           // 0..2047
        int r = chunk >> 5;                // row in tile 0..63
        int c4 = chunk & 31;               // float4 index within row
        int gr = m0 + r;
        float4 u = {0.f, 0.f, 0.f, 0.f};
        if (gr < N_NODES) u = ((const float4*)F)[(size_t)gr * 32 + c4];
        int s    = c4 >> 3;                // k-step 0..3
        int quad = (c4 >> 1) & 3;
        int half = c4 & 1;
        bf16_t* dst = (bf16_t*)&As8[(((r >> 4) * 4 + s) * 4 + quad) * 16 + (r & 15)] + half * 4;
        dst[0] = (bf16_t)u.x; dst[1] = (bf16_t)u.y; dst[2] = (bf16_t)u.z; dst[3] = (bf16_t)u.w;
    }
    __syncthreads();

    const int wave = t >> 6, lane = t & 63;
    const int l15 = lane & 15, quad = lane >> 4;
    const int n0 = wave * 64;

    float bias_v[4];
#pragma unroll
    for (int nt = 0; nt < 4; ++nt) {
        int n = n0 + nt * 16 + l15;
        bias_v[nt] = (n < 128) ? b1[n] : 0.f;
    }

    floatx4 acc[4][4] = {};  // [mt][nt]
#pragma unroll
    for (int s = 0; s < 4; ++s) {
        bf16x8 a[4], b[4];
#pragma unroll
        for (int mt = 0; mt < 4; ++mt)
            a[mt] = As8[(mt * 4 + s) * 64 + lane];
#pragma unroll
        for (int nt = 0; nt < 4; ++nt)
            b[nt] = *(const bf16x8*)(WT + (size_t)(n0 + nt * 16 + l15) * NHID + s * 32 + quad * 8);
#pragma unroll
        for (int mt = 0; mt < 4; ++mt)
#pragma unroll
            for (int nt = 0; nt < 4; ++nt)
                acc[mt][nt] = __builtin_amdgcn_mfma_f32_16x16x32_bf16(a[mt], b[nt], acc[mt][nt], 0, 0, 0);
    }

    // ---- epilogue: acc row = m0 + mt*16 + quad*4 + r, col = n0 + nt*16 + l15
    // Two half-tiles of 32 rows x 256 cols bf16 (16 KB) through LDS.
    // Column swizzle: col' = col ^ (((rl>>2)&3) << 4) -> conflict-free banks.
    bf16_t* Tb = (bf16_t*)As8;
#pragma unroll
    for (int h = 0; h < 2; ++h) {
        __syncthreads();
#pragma unroll
        for (int mi = 0; mi < 2; ++mi) {
            int mt = h * 2 + mi;
#pragma unroll
            for (int r = 0; r < 4; ++r) {
                int rl = mi * 16 + quad * 4 + r;        // 0..31
                int sw = ((rl >> 2) & 3) << 4;
#pragma unroll
                for (int nt = 0; nt < 4; ++nt) {
                    int col = n0 + nt * 16 + l15;
                    Tb[rl * 256 + (col ^ sw)] = (bf16_t)(acc[mt][nt][r] + bias_v[nt]);
                }
            }
        }
        __syncthreads();
#pragma unroll
        for (int j = 0; j < 4; ++j) {
            int chunk = j * 256 + t;       // 0..1023 16B-chunks
            int rl  = chunk >> 5;          // 0..31
            int c16 = chunk & 31;
            int grow = m0 + h * 32 + rl;
            if (grow < N_NODES) {
                bf16x8 v = ((bf16x8*)Tb)[rl * 32 + (c16 ^ ((rl >> 2) & 3) * 2)];
                ((bf16x8*)(PQ + (size_t)grow * PQ_COLS))[c16] = v;
            }
        }
    }
}

// ---------------- kernel 3: per-edge loss, 16 lanes/edge, 4-edge ILP -------
// D = sum_ch h*select(h>=0, wd, wd*alpha) + dbias; loss = softplus(+-D)
__global__ __launch_bounds__(256) void k_edge_loss(const bf16_t* __restrict__ PQ,
                                                   const float* __restrict__ wdp_g,
                                                   const float* __restrict__ wdn_g,
                                                   const float* __restrict__ dbias_g,
                                                   const int* __restrict__ row,
                                                   const int* __restrict__ col,
                                                   const int* __restrict__ label,
                                                   float* __restrict__ out) {
    const int lg = threadIdx.x & 15;                 // lane in 16-lane group
    const int group = (blockIdx.x * blockDim.x + threadIdx.x) >> 4;
    const int ng = (gridDim.x * blockDim.x) >> 4;    // 32768
    const int ch = lg * 8;

    float wdp[8], wdn[8];
#pragma unroll
    for (int j = 0; j < 8; ++j) { wdp[j] = wdp_g[ch + j]; wdn[j] = wdn_g[ch + j]; }
    const float dbias = *dbias_g;

    float acc = 0.f;
    for (int e = group; e < N_EDGES; e += 4 * ng) {
        int ei[4]; bool vl[4];
#pragma unroll
        for (int k = 0; k < 4; ++k) {
            int ee = e + k * ng;
            vl[k] = (ee < N_EDGES);
            ei[k] = vl[k] ? ee : e;
        }
        int r[4], c[4];
#pragma unroll
        for (int k = 0; k < 4; ++k) { r[k] = row[ei[k]]; c[k] = col[ei[k]]; }
        // issue all 8 gathers + 8 label loads before any compute
        bf16x8 p[4], q[4];
#pragma unroll
        for (int k = 0; k < 4; ++k) {
            p[k] = *(const bf16x8*)(PQ + (size_t)r[k] * PQ_COLS + ch);
            q[k] = *(const bf16x8*)(PQ + (size_t)c[k] * PQ_COLS + 128 + ch);
        }
        int yr[4], yc[4];
#pragma unroll
        for (int k = 0; k < 4; ++k) { yr[k] = label[r[k]]; yc[k] = label[c[k]]; }

        float d[4] = {0.f, 0.f, 0.f, 0.f};
#pragma unroll
        for (int j = 0; j < 8; ++j) {
#pragma unroll
            for (int k = 0; k < 4; ++k) {
                float h = (float)p[k][j] + (float)q[k][j];
                d[k] = fmaf(h, (h >= 0.f) ? wdp[j] : wdn[j], d[k]);
            }
        }
#pragma unroll
        for (int m = 8; m >= 1; m >>= 1) {
#pragma unroll
            for (int k = 0; k < 4; ++k) d[k] += __shfl_xor(d[k], m, 16);
        }
        if (lg == 0) {
#pragma unroll
            for (int k = 0; k < 4; ++k) {
                float D = d[k] + dbias;
                float s = (yr[k] == yc[k]) ? -D : D;
                float loss = fmaxf(s, 0.f) + log1pf(expf(-fabsf(s)));
                if (vl[k]) acc += loss;
            }
        }
    }
    // block reduction: wave butterfly then LDS across 4 waves
#pragma unroll
    for (int m = 32; m >= 1; m >>= 1) acc += __shfl_xor(acc, m, 64);
    __shared__ float sdata[4];
    int lane = threadIdx.x & 63;
    int wv = threadIdx.x >> 6;
    if (lane == 0) sdata[wv] = acc;
    __syncthreads();
    if (threadIdx.x == 0) {
        float s = (sdata[0] + sdata[1]) + (sdata[2] + sdata[3]);
        atomicAdd(out, s * (1.f / (float)N_EDGES));
    }
}

extern "C" void kernel_launch(void* const* d_in, const int* in_sizes, int n_in,
                              void* d_out, int out_size, void* d_ws, size_t ws_size,
                              hipStream_t stream) {
    const float* feature = (const float*)d_in[0];   // [100000,128]
    const float* W1      = (const float*)d_in[1];   // [256,128]
    const float* b1      = (const float*)d_in[2];   // [128]
    const float* alpha   = (const float*)d_in[3];   // [128]
    const float* W2      = (const float*)d_in[4];   // [128,2]
    const float* b2      = (const float*)d_in[5];   // [2]
    const int*   row     = (const int*)d_in[6];     // [1M]
    const int*   col     = (const int*)d_in[7];     // [1M]
    const int*   label   = (const int*)d_in[8];     // [100000]
    float* out = (float*)d_out;

    char* ws = (char*)d_ws;
    bf16_t* PQ   = (bf16_t*)(ws);                   // 51,200,000 B
    bf16_t* WT   = (bf16_t*)(ws + 51200000);        // 65,536 B
    float*  wdp  = (float*)(ws + 51265536);         // 512 B
    float*  wdn  = (float*)(ws + 51266048);         // 512 B
    float*  dbias= (float*)(ws + 51266560);         // 4 B

    hipMemsetAsync(d_out, 0, sizeof(float), stream);

    k_prep<<<128, 256, 0, stream>>>(W1, alpha, W2, b2, WT, wdp, wdn, dbias);
    k_gemm_pq<<<1563, 256, 0, stream>>>(feature, WT, b1, PQ);
    k_edge_loss<<<2048, 256, 0, stream>>>(PQ, wdp, wdn, dbias, row, col, label, out);
}

// Round 4
// 210.256 us; speedup vs baseline: 1.3515x; 1.0104x over previous
//
#include <hip/hip_runtime.h>
#include <hip/hip_bf16.h>

typedef __bf16 bf16_t;
typedef bf16_t bf16x8 __attribute__((ext_vector_type(8)));
typedef float floatx4 __attribute__((ext_vector_type(4)));
typedef float floatx2 __attribute__((ext_vector_type(2)));

#define N_NODES 100000
#define N_EDGES 1000000
#define NHID 128
#define PQ_COLS 256

// ---------------- kernel 1: prep ----------------
// blocks 0..127: WT[n][k] = Wcat[k][n] bf16  (Wcat[k,n] = n<128 ? W1[k,n] : W1[k+128,n-128])
// block 128: w1 = wd*(1+a)/2, wabs = wd*(1-a)/2, u1[k]=sum_j W1[k,j]w1[j],
//            u2[k]=sum_j W1[k+128,j]w1[j], CONST = sum w1*b1 + (b2[1]-b2[0])
__global__ __launch_bounds__(256) void k_prep(const float* __restrict__ W1,
                                              const float* __restrict__ b1,
                                              const float* __restrict__ alpha,
                                              const float* __restrict__ W2,
                                              const float* __restrict__ b2,
                                              bf16_t* __restrict__ WT,
                                              float* __restrict__ wabsg,
                                              float* __restrict__ u1g,
                                              float* __restrict__ u2g,
                                              float* __restrict__ constg) {
    __shared__ float w1L[128];
    int i = blockIdx.x * 256 + threadIdx.x;
    if (i < 32768) {
        int n = i >> 7;
        int k = i & 127;
        float v = (n < 128) ? W1[k * 128 + n] : W1[(k + 128) * 128 + (n - 128)];
        WT[i] = (bf16_t)v;
    }
    if (blockIdx.x == 128) {
        int t = threadIdx.x;
        if (t < 128) {
            float wd = W2[2 * t + 1] - W2[2 * t];
            float al = alpha[t];
            w1L[t] = wd * (1.f + al) * 0.5f;
            wabsg[t] = wd * (1.f - al) * 0.5f;
        }
        __syncthreads();
        if (t < 128) {
            float a1 = 0.f, a2 = 0.f;
            for (int j = 0; j < 128; ++j) {
                a1 = fmaf(W1[t * 128 + j], w1L[j], a1);
                a2 = fmaf(W1[(t + 128) * 128 + j], w1L[j], a2);
            }
            u1g[t] = a1;
            u2g[t] = a2;
        }
        if (t == 0) {
            float c = 0.f;
            for (int j = 0; j < 128; ++j) c = fmaf(w1L[j], b1[j], c);
            *constg = c + (b2[1] - b2[0]);
        }
    }
}

// ---------------- kernel 2: PQ8 = fp8(bf16(F) @ Wcat + bias), fused aux ----
__global__ __launch_bounds__(256) void k_gemm_pq(const float* __restrict__ F,
                                                 const bf16_t* __restrict__ WT,
                                                 const float* __restrict__ b1,
                                                 const float* __restrict__ u1g,
                                                 const float* __restrict__ u2g,
                                                 const int* __restrict__ label,
                                                 unsigned char* __restrict__ PQ8,
                                                 float4* __restrict__ aux_g) {
    __shared__ bf16x8 As8[1024];   // 16 KB A-tile (fragment order), reused for epilogue
    __shared__ float sp1[4][64];
    __shared__ float sp2[4][64];
    const int t = threadIdx.x;
    const int m0 = blockIdx.x * 64;

    // ---- stage: 2048 float4 chunks, coalesced; f32->bf16 into LDS fragment order
#pragma unroll
    for (int j = 0; j < 8; ++j) {
        int chunk = j * 256 + t;
        int r = chunk >> 5;
        int c4 = chunk & 31;
        int gr = m0 + r;
        float4 u = {0.f, 0.f, 0.f, 0.f};
        if (gr < N_NODES) u = ((const float4*)F)[(size_t)gr * 32 + c4];
        int s    = c4 >> 3;
        int quad = (c4 >> 1) & 3;
        int half = c4 & 1;
        bf16_t* dst = (bf16_t*)&As8[(((r >> 4) * 4 + s) * 4 + quad) * 16 + (r & 15)] + half * 4;
        dst[0] = (bf16_t)u.x; dst[1] = (bf16_t)u.y; dst[2] = (bf16_t)u.z; dst[3] = (bf16_t)u.w;
    }
    __syncthreads();

    const int wave = t >> 6, lane = t & 63;
    const int l15 = lane & 15, quad = lane >> 4;
    const int n0 = wave * 64;

    float bias_v[4];
#pragma unroll
    for (int nt = 0; nt < 4; ++nt) {
        int n = n0 + nt * 16 + l15;
        bias_v[nt] = (n < 128) ? b1[n] : 0.f;
    }

    floatx4 acc[4][4] = {};
#pragma unroll
    for (int s = 0; s < 4; ++s) {
        bf16x8 a[4], b[4];
#pragma unroll
        for (int mt = 0; mt < 4; ++mt)
            a[mt] = As8[(mt * 4 + s) * 64 + lane];
#pragma unroll
        for (int nt = 0; nt < 4; ++nt)
            b[nt] = *(const bf16x8*)(WT + (size_t)(n0 + nt * 16 + l15) * NHID + s * 32 + quad * 8);
#pragma unroll
        for (int mt = 0; mt < 4; ++mt)
#pragma unroll
            for (int nt = 0; nt < 4; ++nt)
                acc[mt][nt] = __builtin_amdgcn_mfma_f32_16x16x32_bf16(a[mt], b[nt], acc[mt][nt], 0, 0, 0);
    }

    // ---- aux phase: s1 = A.u1, s2 = A.u2 (per row), from LDS A-tile
    {
        int rr = t & 63, part = t >> 6;
        int mt_ = rr >> 4, r15 = rr & 15;
        float a1 = 0.f, a2 = 0.f;
#pragma unroll
        for (int qd = 0; qd < 4; ++qd) {
            bf16x8 av = As8[((mt_ * 4 + part) * 4 + qd) * 16 + r15];
#pragma unroll
            for (int idx = 0; idx < 8; ++idx) {
                float fv = (float)av[idx];
                int kk = part * 32 + qd * 8 + idx;
                a1 = fmaf(fv, u1g[kk], a1);
                a2 = fmaf(fv, u2g[kk], a2);
            }
        }
        sp1[part][rr] = a1;
        sp2[part][rr] = a2;
    }
    __syncthreads();
    if (t < 64) {
        int grow = m0 + t;
        if (grow < N_NODES) {
            float s1 = (sp1[0][t] + sp1[1][t]) + (sp1[2][t] + sp1[3][t]);
            float s2 = (sp2[0][t] + sp2[1][t]) + (sp2[2][t] + sp2[3][t]);
            float4 av = {s1, s2, __int_as_float(label[grow]), 0.f};
            aux_g[grow] = av;
        }
    }

    // ---- epilogue: bf16 LDS transpose (col-swizzled) then fp8 pack + store
    bf16_t* Tb = (bf16_t*)As8;
#pragma unroll
    for (int h = 0; h < 2; ++h) {
        __syncthreads();
#pragma unroll
        for (int mi = 0; mi < 2; ++mi) {
            int mt = h * 2 + mi;
#pragma unroll
            for (int r = 0; r < 4; ++r) {
                int rl = mi * 16 + quad * 4 + r;
                int sw = ((rl >> 2) & 3) << 4;
#pragma unroll
                for (int nt = 0; nt < 4; ++nt) {
                    int colx = n0 + nt * 16 + l15;
                    Tb[rl * 256 + (colx ^ sw)] = (bf16_t)(acc[mt][nt][r] + bias_v[nt]);
                }
            }
        }
        __syncthreads();
#pragma unroll
        for (int j = 0; j < 4; ++j) {
            int chunk = j * 256 + t;       // 0..1023
            int rl  = chunk >> 5;          // 0..31
            int c16 = chunk & 31;
            int grow = m0 + h * 32 + rl;
            if (grow < N_NODES) {
                bf16x8 v = ((bf16x8*)Tb)[rl * 32 + (c16 ^ ((rl >> 2) & 3) * 2)];
                unsigned int lo = 0, hi = 0;
                lo = __builtin_amdgcn_cvt_pk_fp8_f32((float)v[0], (float)v[1], lo, false);
                lo = __builtin_amdgcn_cvt_pk_fp8_f32((float)v[2], (float)v[3], lo, true);
                hi = __builtin_amdgcn_cvt_pk_fp8_f32((float)v[4], (float)v[5], hi, false);
                hi = __builtin_amdgcn_cvt_pk_fp8_f32((float)v[6], (float)v[7], hi, true);
                uint2 pk; pk.x = lo; pk.y = hi;
                ((uint2*)(PQ8 + (size_t)grow * PQ_COLS))[c16] = pk;
            }
        }
    }
}

// ---------------- kernel 3: per-edge loss ----------------
// D = aux[r].s1 + aux[c].s2 + CONST + sum_j wabs_j*|p_j+q_j|; loss = softplus(+-D)
__global__ __launch_bounds__(256) void k_edge_loss(const unsigned char* __restrict__ PQ8,
                                                   const float4* __restrict__ aux,
                                                   const float* __restrict__ wabsg,
                                                   const float* __restrict__ constg,
                                                   const int* __restrict__ row,
                                                   const int* __restrict__ col,
                                                   float* __restrict__ out) {
    const int lg = threadIdx.x & 15;
    const int group = (blockIdx.x * blockDim.x + threadIdx.x) >> 4;
    const int ng = (gridDim.x * blockDim.x) >> 4;
    const int ch = lg * 8;

    float wabs[8];
#pragma unroll
    for (int j = 0; j < 8; ++j) wabs[j] = wabsg[ch + j];
    const float CB = *constg;

    float acc = 0.f;
    for (int e = group; e < N_EDGES; e += 4 * ng) {
        int ei[4]; bool vl[4];
#pragma unroll
        for (int k = 0; k < 4; ++k) {
            int ee = e + k * ng;
            vl[k] = (ee < N_EDGES);
            ei[k] = vl[k] ? ee : e;
        }
        int r[4], c[4];
#pragma unroll
        for (int k = 0; k < 4; ++k) { r[k] = row[ei[k]]; c[k] = col[ei[k]]; }
        uint2 p[4], q[4];
#pragma unroll
        for (int k = 0; k < 4; ++k) {
            p[k] = *(const uint2*)(PQ8 + (size_t)r[k] * PQ_COLS + ch);
            q[k] = *(const uint2*)(PQ8 + (size_t)c[k] * PQ_COLS + 128 + ch);
        }

        float sab[4] = {0.f, 0.f, 0.f, 0.f};
#pragma unroll
        for (int k = 0; k < 4; ++k) {
            floatx2 p01 = __builtin_amdgcn_cvt_pk_f32_fp8((int)p[k].x, false);
            floatx2 p23 = __builtin_amdgcn_cvt_pk_f32_fp8((int)p[k].x, true);
            floatx2 p45 = __builtin_amdgcn_cvt_pk_f32_fp8((int)p[k].y, false);
            floatx2 p67 = __builtin_amdgcn_cvt_pk_f32_fp8((int)p[k].y, true);
            floatx2 q01 = __builtin_amdgcn_cvt_pk_f32_fp8((int)q[k].x, false);
            floatx2 q23 = __builtin_amdgcn_cvt_pk_f32_fp8((int)q[k].x, true);
            floatx2 q45 = __builtin_amdgcn_cvt_pk_f32_fp8((int)q[k].y, false);
            floatx2 q67 = __builtin_amdgcn_cvt_pk_f32_fp8((int)q[k].y, true);
            floatx2 h01 = p01 + q01;
            floatx2 h23 = p23 + q23;
            floatx2 h45 = p45 + q45;
            floatx2 h67 = p67 + q67;
            float s = sab[k];
            s = fmaf(fabsf(h01[0]), wabs[0], s);
            s = fmaf(fabsf(h01[1]), wabs[1], s);
            s = fmaf(fabsf(h23[0]), wabs[2], s);
            s = fmaf(fabsf(h23[1]), wabs[3], s);
            s = fmaf(fabsf(h45[0]), wabs[4], s);
            s = fmaf(fabsf(h45[1]), wabs[5], s);
            s = fmaf(fabsf(h67[0]), wabs[6], s);
            s = fmaf(fabsf(h67[1]), wabs[7], s);
            sab[k] = s;
        }
#pragma unroll
        for (int m = 8; m >= 1; m >>= 1) {
#pragma unroll
            for (int k = 0; k < 4; ++k) sab[k] += __shfl_xor(sab[k], m, 16);
        }
        if (lg == 0) {
#pragma unroll
            for (int k = 0; k < 4; ++k) {
                float4 ar = aux[r[k]];
                float4 ac2 = aux[c[k]];
                float D = ar.x + ac2.y + CB + sab[k];
                float s = (__float_as_int(ar.z) == __float_as_int(ac2.z)) ? -D : D;
                float loss = fmaxf(s, 0.f) + __logf(1.f + __expf(-fabsf(s)));
                if (vl[k]) acc += loss;
            }
        }
    }
#pragma unroll
    for (int m = 32; m >= 1; m >>= 1) acc += __shfl_xor(acc, m, 64);
    __shared__ float sdata[4];
    int lane = threadIdx.x & 63;
    int wv = threadIdx.x >> 6;
    if (lane == 0) sdata[wv] = acc;
    __syncthreads();
    if (threadIdx.x == 0) {
        float s = (sdata[0] + sdata[1]) + (sdata[2] + sdata[3]);
        atomicAdd(out, s * (1.f / (float)N_EDGES));
    }
}

extern "C" void kernel_launch(void* const* d_in, const int* in_sizes, int n_in,
                              void* d_out, int out_size, void* d_ws, size_t ws_size,
                              hipStream_t stream) {
    const float* feature = (const float*)d_in[0];   // [100000,128]
    const float* W1      = (const float*)d_in[1];   // [256,128]
    const float* b1      = (const float*)d_in[2];   // [128]
    const float* alpha   = (const float*)d_in[3];   // [128]
    const float* W2      = (const float*)d_in[4];   // [128,2]
    const float* b2      = (const float*)d_in[5];   // [2]
    const int*   row     = (const int*)d_in[6];     // [1M]
    const int*   col     = (const int*)d_in[7];     // [1M]
    const int*   label   = (const int*)d_in[8];     // [100000]
    float* out = (float*)d_out;

    char* ws = (char*)d_ws;
    unsigned char* PQ8 = (unsigned char*)(ws);      // 100000*256   = 25,600,000 B
    float4* aux  = (float4*)(ws + 25600000);        // 100000*16    =  1,600,000 B
    bf16_t* WT   = (bf16_t*)(ws + 27200000);        // 65,536 B
    float* wabsg = (float*)(ws + 27265536);         // 512 B
    float* u1g   = (float*)(ws + 27266048);         // 512 B
    float* u2g   = (float*)(ws + 27266560);         // 512 B
    float* constg= (float*)(ws + 27267072);         // 4 B

    hipMemsetAsync(d_out, 0, sizeof(float), stream);

    k_prep<<<129, 256, 0, stream>>>(W1, b1, alpha, W2, b2, WT, wabsg, u1g, u2g, constg);
    k_gemm_pq<<<1563, 256, 0, stream>>>(feature, WT, b1, u1g, u2g, label, PQ8, aux);
    k_edge_loss<<<4096, 256, 0, stream>>>(PQ8, aux, wabsg, constg, row, col, out);
}